// Round 1
// baseline (847.118 us; speedup 1.0000x reference)
//
#include <hip/hip_runtime.h>

// GraphSAGE mean-aggregate + linear (no bias): out = (segment_mean(x[src] by dst)) @ W^T
// x: [50000, 64] f32, edge_index: [2, 800000] int32 (jax no-x64 downcasts int64),
// W: [128, 64] f32, out: [50000, 128] f32.

constexpr int N_NODES = 50000;
constexpr int N_EDGES = 800000;
constexpr int IN_CH   = 64;
constexpr int HID_CH  = 128;

__global__ void zero_kernel(float* __restrict__ p, int n) {
    int i = blockIdx.x * blockDim.x + threadIdx.x;
    if (i < n) p[i] = 0.0f;
}

// 16 threads per edge; each thread handles 4 contiguous channels via float4.
__global__ __launch_bounds__(256) void scatter_kernel(
    const float* __restrict__ x,
    const int*   __restrict__ ei,     // [2, N_EDGES]: row0=src, row1=dst
    float*       __restrict__ sums,   // [N_NODES, IN_CH]
    float*       __restrict__ cnts)   // [N_NODES]
{
    int t = blockIdx.x * blockDim.x + threadIdx.x;
    int e = t >> 4;
    if (e >= N_EDGES) return;
    int lane = t & 15;
    int src = ei[e];
    int dst = ei[N_EDGES + e];
    const float4 v = *reinterpret_cast<const float4*>(x + (size_t)src * IN_CH + lane * 4);
    float* s = sums + (size_t)dst * IN_CH + lane * 4;
    atomicAdd(s + 0, v.x);
    atomicAdd(s + 1, v.y);
    atomicAdd(s + 2, v.z);
    atomicAdd(s + 3, v.w);
    if (lane == 0) atomicAdd(cnts + dst, 1.0f);
}

// out[n][o] = (sums[n][:] . W[o][:]) / max(cnt[n], 1)
// W staged in LDS with +1 pad (bank: (o*65+k)%32 = (o+k)%32 -> 2-way alias, free).
__global__ __launch_bounds__(256) void linear_kernel(
    const float* __restrict__ sums,
    const float* __restrict__ cnts,
    const float* __restrict__ W,      // [HID_CH, IN_CH] row-major
    float*       __restrict__ out)    // [N_NODES, HID_CH]
{
    __shared__ float sW[HID_CH][IN_CH + 1];
    __shared__ float sM[2][IN_CH];

    for (int i = threadIdx.x; i < HID_CH * IN_CH; i += blockDim.x) {
        sW[i / IN_CH][i % IN_CH] = W[i];
    }
    __syncthreads();

    const int nl = threadIdx.x >> 7;   // which of the 2 nodes this thread works on
    const int o  = threadIdx.x & 127;  // output channel
    const int npairs = (N_NODES + 1) / 2;

    for (int pair = blockIdx.x; pair < npairs; pair += gridDim.x) {
        const int n0 = pair * 2;
        __syncthreads();  // protect sM from previous iteration's readers
        if (threadIdx.x < 128) {
            int nn = n0 + (threadIdx.x >> 6);
            int k  = threadIdx.x & 63;
            sM[threadIdx.x >> 6][k] = (nn < N_NODES) ? sums[(size_t)nn * IN_CH + k] : 0.0f;
        }
        __syncthreads();

        const int n = n0 + nl;
        if (n < N_NODES) {
            float acc = 0.0f;
            #pragma unroll
            for (int k = 0; k < IN_CH; ++k) {
                acc += sM[nl][k] * sW[o][k];
            }
            const float c = cnts[n];
            out[(size_t)n * HID_CH + o] = acc / fmaxf(c, 1.0f);
        }
    }
}

extern "C" void kernel_launch(void* const* d_in, const int* in_sizes, int n_in,
                              void* d_out, int out_size, void* d_ws, size_t ws_size,
                              hipStream_t stream) {
    const float* x   = (const float*)d_in[0];
    const int*   ei  = (const int*)  d_in[1];
    const float* W   = (const float*)d_in[2];
    float*       out = (float*)d_out;

    float* sums = (float*)d_ws;                       // [N_NODES * IN_CH]
    float* cnts = sums + (size_t)N_NODES * IN_CH;     // [N_NODES], contiguous after sums

    // Zero sums + cnts (ws is poisoned 0xAA before every timed launch).
    const int nz = N_NODES * IN_CH + N_NODES;
    zero_kernel<<<(nz + 255) / 256, 256, 0, stream>>>(sums, nz);

    // Scatter-accumulate: 16 threads/edge.
    const int total = N_EDGES * 16;
    scatter_kernel<<<(total + 255) / 256, 256, 0, stream>>>(x, ei, sums, cnts);

    // Mean + linear.
    linear_kernel<<<1024, 256, 0, stream>>>(sums, cnts, W, out);
}

// Round 2
// 347.956 us; speedup vs baseline: 2.4346x; 2.4346x over previous
//
#include <hip/hip_runtime.h>

// GraphSAGE mean-aggregate + linear (no bias): out = segment_mean(x[src] by dst) @ W^T
// x: [50000, 64] f32, edge_index: [2, 800000] int32, W: [128, 64] f32,
// out: [50000, 128] f32.
//
// Strategy: build CSR (dst -> srcs) on device, then one wave per destination
// node gathers+averages its neighbors in registers and applies the linear
// layer from LDS-staged W. No atomics on the 64-ch payload.

constexpr int N_NODES = 50000;
constexpr int N_EDGES = 800000;
constexpr int IN_CH   = 64;
constexpr int HID_CH  = 128;

__global__ void zero_kernel(int* __restrict__ p, int n) {
    int i = blockIdx.x * blockDim.x + threadIdx.x;
    if (i < n) p[i] = 0;
}

// Degree histogram: one thread per edge, int atomic into 200 KB counts array.
__global__ __launch_bounds__(256) void hist_kernel(
    const int* __restrict__ ei, int* __restrict__ deg)
{
    int e = blockIdx.x * blockDim.x + threadIdx.x;
    if (e >= N_EDGES) return;
    atomicAdd(&deg[ei[N_EDGES + e]], 1);
}

// Exclusive scan of deg[50000] -> offs & cursor. Single block, 1024 threads,
// each thread handles a contiguous chunk; Hillis-Steele over LDS partials.
__global__ __launch_bounds__(1024) void scan_kernel(
    const int* __restrict__ deg, int* __restrict__ offs, int* __restrict__ cursor)
{
    __shared__ int part[1024];
    const int CH = (N_NODES + 1023) / 1024;  // 49
    const int t = threadIdx.x;
    const int base = t * CH;
    int s = 0;
    for (int i = 0; i < CH; ++i) {
        int idx = base + i;
        if (idx < N_NODES) s += deg[idx];
    }
    part[t] = s;
    __syncthreads();
    for (int off = 1; off < 1024; off <<= 1) {
        int v = (t >= off) ? part[t - off] : 0;
        __syncthreads();
        part[t] += v;
        __syncthreads();
    }
    int prefix = (t == 0) ? 0 : part[t - 1];
    for (int i = 0; i < CH; ++i) {
        int idx = base + i;
        if (idx < N_NODES) {
            offs[idx] = prefix;
            cursor[idx] = prefix;
            prefix += deg[idx];
        }
    }
}

// Scatter edges into CSR: pos = cursor[dst]++; csr_src[pos] = src.
__global__ __launch_bounds__(256) void csr_kernel(
    const int* __restrict__ ei, int* __restrict__ cursor, int* __restrict__ csr_src)
{
    int e = blockIdx.x * blockDim.x + threadIdx.x;
    if (e >= N_EDGES) return;
    int src = ei[e];
    int dst = ei[N_EDGES + e];
    int pos = atomicAdd(&cursor[dst], 1);
    csr_src[pos] = src;
}

// One wave per node: gather neighbor rows (lane = channel), mean, then
// out[n][o] = mean . W[o] with W in LDS (pad +1 -> (lane+k)%32 banks, 2-way
// alias across wave64 = free). Each lane produces channels {lane, lane+64}.
__global__ __launch_bounds__(256) void gather_linear_kernel(
    const float* __restrict__ x,
    const int*   __restrict__ csr_src,
    const int*   __restrict__ offs,
    const int*   __restrict__ deg,
    const float* __restrict__ W,
    float*       __restrict__ out)
{
    __shared__ float sW[HID_CH][IN_CH + 1];
    __shared__ float sMean[4][IN_CH];

    for (int i = threadIdx.x; i < HID_CH * IN_CH; i += blockDim.x) {
        sW[i >> 6][i & 63] = W[i];
    }
    __syncthreads();

    const int wave = threadIdx.x >> 6;
    const int lane = threadIdx.x & 63;
    const int wid0 = blockIdx.x * 4 + wave;
    const int nwaves = gridDim.x * 4;

    for (int n = wid0; n < N_NODES; n += nwaves) {
        const int start = offs[n];
        const int d = deg[n];
        const int end = start + d;

        float acc = 0.0f;
        int e = start;
        for (; e + 4 <= end; e += 4) {  // unroll-4: keep 4 row-loads in flight
            int s0 = csr_src[e + 0];
            int s1 = csr_src[e + 1];
            int s2 = csr_src[e + 2];
            int s3 = csr_src[e + 3];
            acc += x[(size_t)s0 * IN_CH + lane];
            acc += x[(size_t)s1 * IN_CH + lane];
            acc += x[(size_t)s2 * IN_CH + lane];
            acc += x[(size_t)s3 * IN_CH + lane];
        }
        for (; e < end; ++e) {
            acc += x[(size_t)csr_src[e] * IN_CH + lane];
        }

        const float inv = 1.0f / fmaxf((float)d, 1.0f);
        sMean[wave][lane] = acc * inv;
        // Same-wave LDS write->read: enforce completion + no reordering.
        __asm__ volatile("s_waitcnt lgkmcnt(0)" ::: "memory");

        float o0 = 0.0f, o1 = 0.0f;
        #pragma unroll
        for (int k = 0; k < IN_CH; ++k) {
            const float m = sMean[wave][k];       // broadcast read: free
            o0 += m * sW[lane][k];
            o1 += m * sW[lane + 64][k];
        }
        out[(size_t)n * HID_CH + lane]      = o0;
        out[(size_t)n * HID_CH + 64 + lane] = o1;
    }
}

extern "C" void kernel_launch(void* const* d_in, const int* in_sizes, int n_in,
                              void* d_out, int out_size, void* d_ws, size_t ws_size,
                              hipStream_t stream) {
    const float* x   = (const float*)d_in[0];
    const int*   ei  = (const int*)  d_in[1];
    const float* W   = (const float*)d_in[2];
    float*       out = (float*)d_out;

    // Workspace layout (ints): deg[N], offs[N], cursor[N], csr_src[E]
    int* deg     = (int*)d_ws;
    int* offs    = deg + N_NODES;
    int* cursor  = offs + N_NODES;
    int* csr_src = cursor + N_NODES;

    zero_kernel<<<(N_NODES + 255) / 256, 256, 0, stream>>>(deg, N_NODES);

    hist_kernel<<<(N_EDGES + 255) / 256, 256, 0, stream>>>(ei, deg);

    scan_kernel<<<1, 1024, 0, stream>>>(deg, offs, cursor);

    csr_kernel<<<(N_EDGES + 255) / 256, 256, 0, stream>>>(ei, cursor, csr_src);

    gather_linear_kernel<<<1024, 256, 0, stream>>>(x, csr_src, offs, deg, W, out);
}

// Round 3
// 259.116 us; speedup vs baseline: 3.2693x; 1.3429x over previous
//
#include <hip/hip_runtime.h>

// GraphSAGE mean-aggregate + linear (no bias): out = segment_mean(x[src] by dst) @ W^T
// x: [50000, 64] f32, edge_index: [2, 800000] int32, W: [128, 64] f32,
// out: [50000, 128] f32.
//
// Pipeline: zero(deg) -> hist -> 3-phase scan -> csr scatter -> fused
// gather+mean+linear (one wave per node, W in registers, no payload atomics).

constexpr int N_NODES = 50000;
constexpr int N_EDGES = 800000;
constexpr int IN_CH   = 64;
constexpr int HID_CH  = 128;
constexpr int SCAN_BS = 256;
constexpr int SCAN_NB = (N_NODES + SCAN_BS - 1) / SCAN_BS;  // 196

__global__ void zero_kernel(int* __restrict__ p, int n) {
    int i = blockIdx.x * blockDim.x + threadIdx.x;
    if (i < n) p[i] = 0;
}

__global__ __launch_bounds__(256) void hist_kernel(
    const int* __restrict__ ei, int* __restrict__ deg)
{
    int e = blockIdx.x * blockDim.x + threadIdx.x;
    if (e >= N_EDGES) return;
    atomicAdd(&deg[ei[N_EDGES + e]], 1);
}

// Scan phase A: per-block sums of deg.
__global__ __launch_bounds__(SCAN_BS) void scan_partial_kernel(
    const int* __restrict__ deg, int* __restrict__ blockSums)
{
    __shared__ int red[SCAN_BS / 64];
    int i = blockIdx.x * SCAN_BS + threadIdx.x;
    int v = (i < N_NODES) ? deg[i] : 0;
    #pragma unroll
    for (int m = 32; m >= 1; m >>= 1) v += __shfl_xor(v, m, 64);
    int wave = threadIdx.x >> 6;
    if ((threadIdx.x & 63) == 0) red[wave] = v;
    __syncthreads();
    if (threadIdx.x == 0) {
        int s = 0;
        #pragma unroll
        for (int w = 0; w < SCAN_BS / 64; ++w) s += red[w];
        blockSums[blockIdx.x] = s;
    }
}

// Scan phase B: single block exclusive-scans the 196 block sums.
__global__ __launch_bounds__(256) void scan_blocksums_kernel(
    const int* __restrict__ blockSums, int* __restrict__ blockOffs,
    int* __restrict__ offs)
{
    __shared__ int sh[256];
    int t = threadIdx.x;
    int v = (t < SCAN_NB) ? blockSums[t] : 0;
    sh[t] = v;
    __syncthreads();
    for (int off = 1; off < 256; off <<= 1) {
        int u = (t >= off) ? sh[t - off] : 0;
        __syncthreads();
        sh[t] += u;
        __syncthreads();
    }
    if (t < SCAN_NB) blockOffs[t] = sh[t] - v;  // exclusive
    if (t == 0) offs[N_NODES] = N_EDGES;        // sentinel
}

// Scan phase C: per-block local exclusive scan + block offset -> offs, cursor.
__global__ __launch_bounds__(SCAN_BS) void scan_final_kernel(
    const int* __restrict__ deg, const int* __restrict__ blockOffs,
    int* __restrict__ offs, int* __restrict__ cursor)
{
    __shared__ int sh[SCAN_BS];
    int t = threadIdx.x;
    int i = blockIdx.x * SCAN_BS + t;
    int v = (i < N_NODES) ? deg[i] : 0;
    sh[t] = v;
    __syncthreads();
    for (int off = 1; off < SCAN_BS; off <<= 1) {
        int u = (t >= off) ? sh[t - off] : 0;
        __syncthreads();
        sh[t] += u;
        __syncthreads();
    }
    if (i < N_NODES) {
        int excl = sh[t] - v + blockOffs[blockIdx.x];
        offs[i] = excl;
        cursor[i] = excl;
    }
}

__global__ __launch_bounds__(256) void csr_kernel(
    const int* __restrict__ ei, int* __restrict__ cursor, int* __restrict__ csr_src)
{
    int e = blockIdx.x * blockDim.x + threadIdx.x;
    if (e >= N_EDGES) return;
    int src = ei[e];
    int dst = ei[N_EDGES + e];
    int pos = atomicAdd(&cursor[dst], 1);
    csr_src[pos] = src;
}

// One wave per node. Gather: 16 lanes per row (float4/lane), 4 edges per wave
// iteration; butterfly shfl_xor merges the 4 edge groups. Linear: W rows
// {lane, lane+64} held in registers; mean channel k broadcast via __shfl with
// compile-time source lane; 1/deg folded into the epilogue.
__global__ __launch_bounds__(256) void gather_linear_kernel(
    const float* __restrict__ x,
    const int*   __restrict__ csr_src,
    const int*   __restrict__ offs,
    const float* __restrict__ W,
    float*       __restrict__ out)
{
    const int wave = threadIdx.x >> 6;
    const int lane = threadIdx.x & 63;
    const int grp  = lane >> 4;   // which of 4 edges in a wave iteration
    const int ch4  = lane & 15;   // float4 slot: channels ch4*4 .. ch4*4+3

    // W rows for output channels `lane` and `lane+64` -> registers.
    float w0[IN_CH], w1[IN_CH];
    #pragma unroll
    for (int k4 = 0; k4 < IN_CH / 4; ++k4) {
        const float4 a = *reinterpret_cast<const float4*>(W + (size_t)lane * IN_CH + k4 * 4);
        const float4 b = *reinterpret_cast<const float4*>(W + (size_t)(lane + 64) * IN_CH + k4 * 4);
        w0[k4 * 4 + 0] = a.x; w0[k4 * 4 + 1] = a.y; w0[k4 * 4 + 2] = a.z; w0[k4 * 4 + 3] = a.w;
        w1[k4 * 4 + 0] = b.x; w1[k4 * 4 + 1] = b.y; w1[k4 * 4 + 2] = b.z; w1[k4 * 4 + 3] = b.w;
    }

    const int wid0   = blockIdx.x * 4 + wave;
    const int nwaves = gridDim.x * 4;

    for (int n = wid0; n < N_NODES; n += nwaves) {
        const int start = offs[n];
        const int end   = offs[n + 1];
        const int d     = end - start;

        float a0 = 0.f, a1 = 0.f, a2 = 0.f, a3 = 0.f;
        int e0 = start;
        for (; e0 + 8 <= end; e0 += 8) {   // two 4-edge groups in flight
            int sA = csr_src[e0 + grp];
            int sB = csr_src[e0 + 4 + grp];
            const float4 vA = *reinterpret_cast<const float4*>(x + (size_t)sA * IN_CH + ch4 * 4);
            const float4 vB = *reinterpret_cast<const float4*>(x + (size_t)sB * IN_CH + ch4 * 4);
            a0 += vA.x + vB.x; a1 += vA.y + vB.y; a2 += vA.z + vB.z; a3 += vA.w + vB.w;
        }
        for (; e0 + 4 <= end; e0 += 4) {
            int s = csr_src[e0 + grp];
            const float4 v = *reinterpret_cast<const float4*>(x + (size_t)s * IN_CH + ch4 * 4);
            a0 += v.x; a1 += v.y; a2 += v.z; a3 += v.w;
        }
        if (e0 < end) {                    // tail: 1-3 edges
            int eg = e0 + grp;
            if (eg < end) {
                int s = csr_src[eg];
                const float4 v = *reinterpret_cast<const float4*>(x + (size_t)s * IN_CH + ch4 * 4);
                a0 += v.x; a1 += v.y; a2 += v.z; a3 += v.w;
            }
        }
        // Merge the 4 edge groups: every lane ends with the full channel sums
        // for its ch4 slot.
        #pragma unroll
        for (int m = 16; m <= 32; m <<= 1) {
            a0 += __shfl_xor(a0, m, 64);
            a1 += __shfl_xor(a1, m, 64);
            a2 += __shfl_xor(a2, m, 64);
            a3 += __shfl_xor(a3, m, 64);
        }

        float o0 = 0.f, o1 = 0.f;
        #pragma unroll
        for (int k = 0; k < IN_CH; ++k) {
            // channel k lives in lane (k>>2) (group 0 copy), component k&3
            float comp = (k & 3) == 0 ? a0 : (k & 3) == 1 ? a1 : (k & 3) == 2 ? a2 : a3;
            float m = __shfl(comp, k >> 2, 64);
            o0 += m * w0[k];
            o1 += m * w1[k];
        }
        const float inv = 1.0f / fmaxf((float)d, 1.0f);
        out[(size_t)n * HID_CH + lane]      = o0 * inv;
        out[(size_t)n * HID_CH + 64 + lane] = o1 * inv;
    }
}

extern "C" void kernel_launch(void* const* d_in, const int* in_sizes, int n_in,
                              void* d_out, int out_size, void* d_ws, size_t ws_size,
                              hipStream_t stream) {
    const float* x   = (const float*)d_in[0];
    const int*   ei  = (const int*)  d_in[1];
    const float* W   = (const float*)d_in[2];
    float*       out = (float*)d_out;

    // Workspace (ints): deg[N], offs[N+1], cursor[N], blockSums[NB], blockOffs[NB], csr_src[E]
    int* deg       = (int*)d_ws;
    int* offs      = deg + N_NODES;
    int* cursor    = offs + N_NODES + 1;
    int* blockSums = cursor + N_NODES;
    int* blockOffs = blockSums + SCAN_NB;
    int* csr_src   = blockOffs + SCAN_NB;

    zero_kernel<<<(N_NODES + 255) / 256, 256, 0, stream>>>(deg, N_NODES);
    hist_kernel<<<(N_EDGES + 255) / 256, 256, 0, stream>>>(ei, deg);
    scan_partial_kernel<<<SCAN_NB, SCAN_BS, 0, stream>>>(deg, blockSums);
    scan_blocksums_kernel<<<1, 256, 0, stream>>>(blockSums, blockOffs, offs);
    scan_final_kernel<<<SCAN_NB, SCAN_BS, 0, stream>>>(deg, blockOffs, offs, cursor);
    csr_kernel<<<(N_EDGES + 255) / 256, 256, 0, stream>>>(ei, cursor, csr_src);
    gather_linear_kernel<<<1024, 256, 0, stream>>>(x, csr_src, offs, W, out);
}

// Round 4
// 199.159 us; speedup vs baseline: 4.2535x; 1.3011x over previous
//
#include <hip/hip_runtime.h>

// GraphSAGE mean-aggregate + linear (no bias): out = segment_mean(x[src] by dst) @ W^T
// x: [50000, 64] f32, edge_index: [2, 800000] int32, W: [128, 64] f32,
// out: [50000, 128] f32.
//
// Pipeline: memset(deg) -> hist -> scanA -> scanC(fused B+C) -> csr scatter
//   -> gather_sum (one wave per node, pure gather, writes fp32 sums)
//   -> gemm (mean + W^T, W in LDS once per block, reg-blocked 4 nodes x 2 outs).

constexpr int N_NODES = 50000;
constexpr int N_EDGES = 800000;
constexpr int IN_CH   = 64;
constexpr int HID_CH  = 128;
constexpr int SCAN_BS = 256;
constexpr int SCAN_NB = (N_NODES + SCAN_BS - 1) / SCAN_BS;  // 196

// ---- degree histogram: 4 edges/thread via int4 ----
__global__ __launch_bounds__(256) void hist_kernel(
    const int* __restrict__ ei, int* __restrict__ deg)
{
    int i = blockIdx.x * blockDim.x + threadIdx.x;
    if (i * 4 >= N_EDGES) return;
    const int4 d4 = *reinterpret_cast<const int4*>(ei + N_EDGES + i * 4);
    atomicAdd(&deg[d4.x], 1);
    atomicAdd(&deg[d4.y], 1);
    atomicAdd(&deg[d4.z], 1);
    atomicAdd(&deg[d4.w], 1);
}

// ---- scan phase A: per-block sums of deg ----
__global__ __launch_bounds__(SCAN_BS) void scan_partial_kernel(
    const int* __restrict__ deg, int* __restrict__ blockSums)
{
    __shared__ int red[SCAN_BS / 64];
    int i = blockIdx.x * SCAN_BS + threadIdx.x;
    int v = (i < N_NODES) ? deg[i] : 0;
    #pragma unroll
    for (int m = 32; m >= 1; m >>= 1) v += __shfl_xor(v, m, 64);
    if ((threadIdx.x & 63) == 0) red[threadIdx.x >> 6] = v;
    __syncthreads();
    if (threadIdx.x == 0) {
        int s = 0;
        #pragma unroll
        for (int w = 0; w < SCAN_BS / 64; ++w) s += red[w];
        blockSums[blockIdx.x] = s;
    }
}

// ---- scan phase C (fused with B): every block scans the 196 block sums
//      itself, plus its local chunk; writes offs & cursor ----
__global__ __launch_bounds__(SCAN_BS) void scan_final_kernel(
    const int* __restrict__ deg, const int* __restrict__ blockSums,
    int* __restrict__ offs, int* __restrict__ cursor)
{
    __shared__ int bs[SCAN_BS];
    __shared__ int sh[SCAN_BS];
    const int t = threadIdx.x;
    const int i = blockIdx.x * SCAN_BS + t;
    int bv = (t < SCAN_NB) ? blockSums[t] : 0;
    int v  = (i < N_NODES) ? deg[i] : 0;
    bs[t] = bv;
    sh[t] = v;
    __syncthreads();
    for (int off = 1; off < SCAN_BS; off <<= 1) {
        int u1 = (t >= off) ? bs[t - off] : 0;
        int u2 = (t >= off) ? sh[t - off] : 0;
        __syncthreads();
        bs[t] += u1;
        sh[t] += u2;
        __syncthreads();
    }
    const int blockOff = (blockIdx.x == 0) ? 0 : bs[blockIdx.x - 1];
    if (i < N_NODES) {
        int excl = sh[t] - v + blockOff;
        offs[i] = excl;
        cursor[i] = excl;
    }
    if (blockIdx.x == 0 && t == 0) offs[N_NODES] = N_EDGES;  // sentinel
}

// ---- CSR scatter: 4 edges/thread ----
__global__ __launch_bounds__(256) void csr_kernel(
    const int* __restrict__ ei, int* __restrict__ cursor, int* __restrict__ csr_src)
{
    int i = blockIdx.x * blockDim.x + threadIdx.x;
    if (i * 4 >= N_EDGES) return;
    const int4 s4 = *reinterpret_cast<const int4*>(ei + i * 4);
    const int4 d4 = *reinterpret_cast<const int4*>(ei + N_EDGES + i * 4);
    csr_src[atomicAdd(&cursor[d4.x], 1)] = s4.x;
    csr_src[atomicAdd(&cursor[d4.y], 1)] = s4.y;
    csr_src[atomicAdd(&cursor[d4.z], 1)] = s4.z;
    csr_src[atomicAdd(&cursor[d4.w], 1)] = s4.w;
}

// ---- gather: one wave per node, 16 lanes x float4 per row, 16 edges in
//      flight per burst; indices loaded coalesced once, broadcast via shfl.
//      Writes raw fp32 sums (no epilogue). ----
__global__ __launch_bounds__(256) void gather_sum_kernel(
    const float* __restrict__ x,
    const int*   __restrict__ csr_src,
    const int*   __restrict__ offs,
    float*       __restrict__ sums)
{
    const int wave = threadIdx.x >> 6;
    const int lane = threadIdx.x & 63;
    const int grp  = lane >> 4;
    const int ch4  = lane & 15;
    const int wid0 = blockIdx.x * 4 + wave;
    const int nw   = gridDim.x * 4;

    for (int n = wid0; n < N_NODES; n += nw) {
        const int start = offs[n];
        const int end   = offs[n + 1];
        float a0 = 0.f, a1 = 0.f, a2 = 0.f, a3 = 0.f;

        for (int base = start; base < end; base += 64) {
            const int cnt = min(end - base, 64);
            int idx = 0;
            if (lane < cnt) idx = csr_src[base + lane];
            const int nIt = (cnt + 3) >> 2;
            for (int i = 0; i < nIt; i += 4) {
                const int e0 = 4 * i + grp;
                const int e1 = e0 + 4, e2 = e0 + 8, e3 = e0 + 12;
                const int s0 = __shfl(idx, e0 & 63, 64);
                const int s1 = __shfl(idx, e1 & 63, 64);
                const int s2 = __shfl(idx, e2 & 63, 64);
                const int s3 = __shfl(idx, e3 & 63, 64);
                const float f0 = (e0 < cnt) ? 1.f : 0.f;
                const float f1 = (e1 < cnt) ? 1.f : 0.f;
                const float f2 = (e2 < cnt) ? 1.f : 0.f;
                const float f3 = (e3 < cnt) ? 1.f : 0.f;
                const float4 v0 = *reinterpret_cast<const float4*>(x + (size_t)s0 * IN_CH + ch4 * 4);
                const float4 v1 = *reinterpret_cast<const float4*>(x + (size_t)s1 * IN_CH + ch4 * 4);
                const float4 v2 = *reinterpret_cast<const float4*>(x + (size_t)s2 * IN_CH + ch4 * 4);
                const float4 v3 = *reinterpret_cast<const float4*>(x + (size_t)s3 * IN_CH + ch4 * 4);
                a0 = fmaf(f0, v0.x, a0); a1 = fmaf(f0, v0.y, a1);
                a2 = fmaf(f0, v0.z, a2); a3 = fmaf(f0, v0.w, a3);
                a0 = fmaf(f1, v1.x, a0); a1 = fmaf(f1, v1.y, a1);
                a2 = fmaf(f1, v1.z, a2); a3 = fmaf(f1, v1.w, a3);
                a0 = fmaf(f2, v2.x, a0); a1 = fmaf(f2, v2.y, a1);
                a2 = fmaf(f2, v2.z, a2); a3 = fmaf(f2, v2.w, a3);
                a0 = fmaf(f3, v3.x, a0); a1 = fmaf(f3, v3.y, a1);
                a2 = fmaf(f3, v3.z, a2); a3 = fmaf(f3, v3.w, a3);
            }
        }
        // merge the 4 edge groups
        #pragma unroll
        for (int m = 16; m <= 32; m <<= 1) {
            a0 += __shfl_xor(a0, m, 64);
            a1 += __shfl_xor(a1, m, 64);
            a2 += __shfl_xor(a2, m, 64);
            a3 += __shfl_xor(a3, m, 64);
        }
        if (lane < 16) {
            float4 r{a0, a1, a2, a3};
            *reinterpret_cast<float4*>(sums + (size_t)n * IN_CH + ch4 * 4) = r;
        }
    }
}

// ---- mean + linear as a tiny tiled GEMM: 16 nodes/block, W staged in LDS
//      once, each thread computes 4 nodes x 2 output channels ----
__global__ __launch_bounds__(256) void gemm_kernel(
    const float* __restrict__ sums,
    const int*   __restrict__ deg,
    const float* __restrict__ W,
    float*       __restrict__ out)
{
    __shared__ float4 sW4[16][HID_CH + 1];  // [k4][o] = W[o][4k4..+3]; +1 pad
    __shared__ float4 sA4[16][16];          // [node][k4] mean, broadcast-read

    const int t = threadIdx.x;
    #pragma unroll
    for (int r = 0; r < 8; ++r) {
        int i = t + r * 256;                // 0..2047
        int o = i >> 4, k4 = i & 15;        // coalesced global read over k4
        sW4[k4][o] = *reinterpret_cast<const float4*>(W + (size_t)o * IN_CH + k4 * 4);
    }
    const int n0 = blockIdx.x * 16;
    {
        int node = n0 + (t >> 4);
        int k4 = t & 15;
        float4 v = *reinterpret_cast<const float4*>(sums + (size_t)node * IN_CH + k4 * 4);
        float inv = 1.0f / fmaxf((float)deg[node], 1.0f);
        v.x *= inv; v.y *= inv; v.z *= inv; v.w *= inv;
        sA4[t >> 4][k4] = v;
    }
    __syncthreads();

    const int wave = t >> 6;
    const int lane = t & 63;
    const int nb = wave * 4;  // this wave's 4 nodes within the tile

    float acc[4][2] = {{0.f, 0.f}, {0.f, 0.f}, {0.f, 0.f}, {0.f, 0.f}};
    #pragma unroll
    for (int k4 = 0; k4 < 16; ++k4) {
        const float4 w0 = sW4[k4][lane];
        const float4 w1 = sW4[k4][lane + 64];
        #pragma unroll
        for (int j = 0; j < 4; ++j) {
            const float4 a = sA4[nb + j][k4];  // same addr across wave: broadcast
            acc[j][0] += a.x * w0.x + a.y * w0.y + a.z * w0.z + a.w * w0.w;
            acc[j][1] += a.x * w1.x + a.y * w1.y + a.z * w1.z + a.w * w1.w;
        }
    }
    #pragma unroll
    for (int j = 0; j < 4; ++j) {
        const size_t row = (size_t)(n0 + nb + j) * HID_CH;
        out[row + lane]      = acc[j][0];
        out[row + 64 + lane] = acc[j][1];
    }
}

extern "C" void kernel_launch(void* const* d_in, const int* in_sizes, int n_in,
                              void* d_out, int out_size, void* d_ws, size_t ws_size,
                              hipStream_t stream) {
    const float* x   = (const float*)d_in[0];
    const int*   ei  = (const int*)  d_in[1];
    const float* W   = (const float*)d_in[2];
    float*       out = (float*)d_out;

    // Workspace: deg[N], offs[N+1], cursor[N], blockSums[NB], csr_src[E], sums[N*64]f
    int* deg       = (int*)d_ws;
    int* offs      = deg + N_NODES;
    int* cursor    = offs + N_NODES + 1;
    int* blockSums = cursor + N_NODES;
    int* csr_src   = blockSums + SCAN_NB;
    float* sums    = (float*)(csr_src + N_EDGES);

    hipMemsetAsync(deg, 0, N_NODES * sizeof(int), stream);
    hist_kernel<<<(N_EDGES / 4 + 255) / 256, 256, 0, stream>>>(ei, deg);
    scan_partial_kernel<<<SCAN_NB, SCAN_BS, 0, stream>>>(deg, blockSums);
    scan_final_kernel<<<SCAN_NB, SCAN_BS, 0, stream>>>(deg, blockSums, offs, cursor);
    csr_kernel<<<(N_EDGES / 4 + 255) / 256, 256, 0, stream>>>(ei, cursor, csr_src);
    gather_sum_kernel<<<N_NODES / 16, 256, 0, stream>>>(x, csr_src, offs, sums);  // 3125 blocks, 4 nodes/wave
    gemm_kernel<<<N_NODES / 16, 256, 0, stream>>>(sums, deg, W, out);
}

// Round 5
// 142.095 us; speedup vs baseline: 5.9616x; 1.4016x over previous
//
#include <hip/hip_runtime.h>

// GraphSAGE mean-aggregate + linear (no bias): out = segment_mean(x[src] by dst) @ W^T
// x: [50000, 64] f32, edge_index: [2, 800000] int32, W: [128, 64] f32,
// out: [50000, 128] f32.
//
// Pipeline: memset(bucketCursor) -> bin (bucket sort by dst/196, LDS-staged,
// coalesced) -> csr_build (per-bucket local CSR in LDS, coalesced) ->
// gather_sum (one wave per node) -> gemm (mean + W^T).

constexpr int N_NODES = 50000;
constexpr int N_EDGES = 800000;
constexpr int IN_CH   = 64;
constexpr int HID_CH  = 128;

constexpr int NBKT          = 256;
constexpr int NODES_PER_BKT = 196;   // 256*196 = 50176 >= 50000; bucket = dst/196
constexpr int BKT_CAP       = 4096;  // mean 3125, max ~3.3K -> safe
constexpr int CHUNK         = 4096;  // edges per binning block
constexpr int NBIN_BLOCKS   = (N_EDGES + CHUNK - 1) / CHUNK;  // 196

// ---- pass 1: bucket-bin edges. LDS histogram + local sort, coalesced out ----
__global__ __launch_bounds__(256) void bin_kernel(
    const int* __restrict__ ei,
    int* __restrict__ cursor,                       // [NBKT], zeroed
    unsigned long long* __restrict__ binned)        // [NBKT][BKT_CAP] (dst<<32)|src
{
    __shared__ int hist[NBKT];
    __shared__ int scan[NBKT];   // inclusive scan workspace
    __shared__ int lexcl[NBKT];  // local exclusive base per bucket
    __shared__ int lcur[NBKT];
    __shared__ int res[NBKT];    // reserved global slot within bucket
    __shared__ unsigned long long stage[CHUNK];

    const int t  = threadIdx.x;
    const int e0 = blockIdx.x * CHUNK;
    const int nE = min(N_EDGES - e0, CHUNK);

    hist[t] = 0;
    __syncthreads();

    int srcs[16], dsts[16];
    #pragma unroll
    for (int q = 0; q < 4; ++q) {
        const int idx = t * 16 + q * 4;
        if (idx < nE) {  // nE % 4 == 0 always
            const int4 s4 = *reinterpret_cast<const int4*>(ei + e0 + idx);
            const int4 d4 = *reinterpret_cast<const int4*>(ei + N_EDGES + e0 + idx);
            srcs[q * 4 + 0] = s4.x; srcs[q * 4 + 1] = s4.y;
            srcs[q * 4 + 2] = s4.z; srcs[q * 4 + 3] = s4.w;
            dsts[q * 4 + 0] = d4.x; dsts[q * 4 + 1] = d4.y;
            dsts[q * 4 + 2] = d4.z; dsts[q * 4 + 3] = d4.w;
            atomicAdd(&hist[d4.x / NODES_PER_BKT], 1);
            atomicAdd(&hist[d4.y / NODES_PER_BKT], 1);
            atomicAdd(&hist[d4.z / NODES_PER_BKT], 1);
            atomicAdd(&hist[d4.w / NODES_PER_BKT], 1);
        } else {
            srcs[q*4+0]=srcs[q*4+1]=srcs[q*4+2]=srcs[q*4+3]=0;
            dsts[q*4+0]=dsts[q*4+1]=dsts[q*4+2]=dsts[q*4+3]=0;
        }
    }
    __syncthreads();

    const int hv = hist[t];
    scan[t] = hv;
    __syncthreads();
    for (int off = 1; off < NBKT; off <<= 1) {
        const int u = (t >= off) ? scan[t - off] : 0;
        __syncthreads();
        scan[t] += u;
        __syncthreads();
    }
    const int myExcl = scan[t] - hv;
    lexcl[t] = myExcl;
    lcur[t]  = myExcl;
    res[t]   = (hv > 0) ? atomicAdd(&cursor[t], hv) : 0;
    __syncthreads();

    #pragma unroll
    for (int q = 0; q < 16; ++q) {
        const int idx = t * 16 + q;
        if (idx < nE) {
            const int bkt = dsts[q] / NODES_PER_BKT;
            const int p = atomicAdd(&lcur[bkt], 1);
            stage[p] = ((unsigned long long)(unsigned)dsts[q] << 32) | (unsigned)srcs[q];
        }
    }
    __syncthreads();

    for (int i = t; i < nE; i += 256) {
        const unsigned long long v = stage[i];
        const int bkt = (int)(v >> 32) / NODES_PER_BKT;
        const int p = res[bkt] + (i - lexcl[bkt]);
        if (p < BKT_CAP) binned[(size_t)bkt * BKT_CAP + p] = v;
    }
}

// ---- pass 2: one block per bucket -> offs, deg, csr_src (all coalesced) ----
__global__ __launch_bounds__(256) void csr_build_kernel(
    const unsigned long long* __restrict__ binned,
    const int* __restrict__ cursor,
    int* __restrict__ offs,      // [N_NODES+1]
    int* __restrict__ deg,       // [N_NODES]
    int* __restrict__ csr_src)   // [N_EDGES]
{
    __shared__ int bsum[NBKT];
    __shared__ int ldeg[NODES_PER_BKT];
    __shared__ int lscan[NBKT];
    __shared__ int lcur[NODES_PER_BKT];
    __shared__ int stage_src[BKT_CAP];

    const int b = blockIdx.x;
    const int t = threadIdx.x;

    // scan of bucket counts -> edge base for this bucket
    const int cAll = min(cursor[t], BKT_CAP);
    bsum[t] = cAll;
    if (t < NODES_PER_BKT) ldeg[t] = 0;
    __syncthreads();
    for (int off = 1; off < NBKT; off <<= 1) {
        const int u = (t >= off) ? bsum[t - off] : 0;
        __syncthreads();
        bsum[t] += u;
        __syncthreads();
    }
    const int cnt   = min(cursor[b], BKT_CAP);
    const int ebase = bsum[b] - cnt;
    const int nodeBase = b * NODES_PER_BKT;

    unsigned long long ev[16];
    #pragma unroll
    for (int q = 0; q < 16; ++q) {
        const int i = t + q * 256;
        ev[q] = 0;
        if (i < cnt) {
            ev[q] = binned[(size_t)b * BKT_CAP + i];
            atomicAdd(&ldeg[(int)(ev[q] >> 32) - nodeBase], 1);
        }
    }
    __syncthreads();

    const int dv = (t < NODES_PER_BKT) ? ldeg[t] : 0;
    lscan[t] = dv;
    __syncthreads();
    for (int off = 1; off < NBKT; off <<= 1) {
        const int u = (t >= off) ? lscan[t - off] : 0;
        __syncthreads();
        lscan[t] += u;
        __syncthreads();
    }
    const int nNodes = min(N_NODES - nodeBase, NODES_PER_BKT);
    if (t < nNodes) {
        const int excl = lscan[t] - dv;
        offs[nodeBase + t] = ebase + excl;
        deg[nodeBase + t]  = dv;
        lcur[t] = excl;
    }
    if (b == NBKT - 1 && t == 0) offs[N_NODES] = N_EDGES;
    __syncthreads();

    #pragma unroll
    for (int q = 0; q < 16; ++q) {
        const int i = t + q * 256;
        if (i < cnt) {
            const int loc = (int)(ev[q] >> 32) - nodeBase;
            const int p = atomicAdd(&lcur[loc], 1);
            stage_src[p] = (int)(ev[q] & 0xffffffffu);
        }
    }
    __syncthreads();

    for (int i = t; i < cnt; i += 256) {
        csr_src[ebase + i] = stage_src[i];
    }
}

// ---- gather: one wave per node, 16 lanes x float4 per row, 16 edges in
//      flight per burst; indices loaded coalesced once, broadcast via shfl ----
__global__ __launch_bounds__(256) void gather_sum_kernel(
    const float* __restrict__ x,
    const int*   __restrict__ csr_src,
    const int*   __restrict__ offs,
    float*       __restrict__ sums)
{
    const int wave = threadIdx.x >> 6;
    const int lane = threadIdx.x & 63;
    const int grp  = lane >> 4;
    const int ch4  = lane & 15;
    const int wid0 = blockIdx.x * 4 + wave;
    const int nw   = gridDim.x * 4;

    for (int n = wid0; n < N_NODES; n += nw) {
        const int start = offs[n];
        const int end   = offs[n + 1];
        float a0 = 0.f, a1 = 0.f, a2 = 0.f, a3 = 0.f;

        for (int base = start; base < end; base += 64) {
            const int cnt = min(end - base, 64);
            int idx = 0;
            if (lane < cnt) idx = csr_src[base + lane];
            const int nIt = (cnt + 3) >> 2;
            for (int i = 0; i < nIt; i += 4) {
                const int e0 = 4 * i + grp;
                const int e1 = e0 + 4, e2 = e0 + 8, e3 = e0 + 12;
                const int s0 = __shfl(idx, e0 & 63, 64);
                const int s1 = __shfl(idx, e1 & 63, 64);
                const int s2 = __shfl(idx, e2 & 63, 64);
                const int s3 = __shfl(idx, e3 & 63, 64);
                const float f0 = (e0 < cnt) ? 1.f : 0.f;
                const float f1 = (e1 < cnt) ? 1.f : 0.f;
                const float f2 = (e2 < cnt) ? 1.f : 0.f;
                const float f3 = (e3 < cnt) ? 1.f : 0.f;
                const float4 v0 = *reinterpret_cast<const float4*>(x + (size_t)s0 * IN_CH + ch4 * 4);
                const float4 v1 = *reinterpret_cast<const float4*>(x + (size_t)s1 * IN_CH + ch4 * 4);
                const float4 v2 = *reinterpret_cast<const float4*>(x + (size_t)s2 * IN_CH + ch4 * 4);
                const float4 v3 = *reinterpret_cast<const float4*>(x + (size_t)s3 * IN_CH + ch4 * 4);
                a0 = fmaf(f0, v0.x, a0); a1 = fmaf(f0, v0.y, a1);
                a2 = fmaf(f0, v0.z, a2); a3 = fmaf(f0, v0.w, a3);
                a0 = fmaf(f1, v1.x, a0); a1 = fmaf(f1, v1.y, a1);
                a2 = fmaf(f1, v1.z, a2); a3 = fmaf(f1, v1.w, a3);
                a0 = fmaf(f2, v2.x, a0); a1 = fmaf(f2, v2.y, a1);
                a2 = fmaf(f2, v2.z, a2); a3 = fmaf(f2, v2.w, a3);
                a0 = fmaf(f3, v3.x, a0); a1 = fmaf(f3, v3.y, a1);
                a2 = fmaf(f3, v3.z, a2); a3 = fmaf(f3, v3.w, a3);
            }
        }
        #pragma unroll
        for (int m = 16; m <= 32; m <<= 1) {
            a0 += __shfl_xor(a0, m, 64);
            a1 += __shfl_xor(a1, m, 64);
            a2 += __shfl_xor(a2, m, 64);
            a3 += __shfl_xor(a3, m, 64);
        }
        if (lane < 16) {
            float4 r{a0, a1, a2, a3};
            *reinterpret_cast<float4*>(sums + (size_t)n * IN_CH + ch4 * 4) = r;
        }
    }
}

// ---- mean + linear as a tiny tiled GEMM: 16 nodes/block, W staged in LDS ----
__global__ __launch_bounds__(256) void gemm_kernel(
    const float* __restrict__ sums,
    const int*   __restrict__ deg,
    const float* __restrict__ W,
    float*       __restrict__ out)
{
    __shared__ float4 sW4[16][HID_CH + 1];
    __shared__ float4 sA4[16][16];

    const int t = threadIdx.x;
    #pragma unroll
    for (int r = 0; r < 8; ++r) {
        int i = t + r * 256;
        int o = i >> 4, k4 = i & 15;
        sW4[k4][o] = *reinterpret_cast<const float4*>(W + (size_t)o * IN_CH + k4 * 4);
    }
    const int n0 = blockIdx.x * 16;
    {
        int node = n0 + (t >> 4);
        int k4 = t & 15;
        float4 v = *reinterpret_cast<const float4*>(sums + (size_t)node * IN_CH + k4 * 4);
        float inv = 1.0f / fmaxf((float)deg[node], 1.0f);
        v.x *= inv; v.y *= inv; v.z *= inv; v.w *= inv;
        sA4[t >> 4][k4] = v;
    }
    __syncthreads();

    const int wave = t >> 6;
    const int lane = t & 63;
    const int nb = wave * 4;

    float acc[4][2] = {{0.f, 0.f}, {0.f, 0.f}, {0.f, 0.f}, {0.f, 0.f}};
    #pragma unroll
    for (int k4 = 0; k4 < 16; ++k4) {
        const float4 w0 = sW4[k4][lane];
        const float4 w1 = sW4[k4][lane + 64];
        #pragma unroll
        for (int j = 0; j < 4; ++j) {
            const float4 a = sA4[nb + j][k4];
            acc[j][0] += a.x * w0.x + a.y * w0.y + a.z * w0.z + a.w * w0.w;
            acc[j][1] += a.x * w1.x + a.y * w1.y + a.z * w1.z + a.w * w1.w;
        }
    }
    #pragma unroll
    for (int j = 0; j < 4; ++j) {
        const size_t row = (size_t)(n0 + nb + j) * HID_CH;
        out[row + lane]      = acc[j][0];
        out[row + 64 + lane] = acc[j][1];
    }
}

extern "C" void kernel_launch(void* const* d_in, const int* in_sizes, int n_in,
                              void* d_out, int out_size, void* d_ws, size_t ws_size,
                              hipStream_t stream) {
    const float* x   = (const float*)d_in[0];
    const int*   ei  = (const int*)  d_in[1];
    const float* W   = (const float*)d_in[2];
    float*       out = (float*)d_out;

    // ws layout (binned first for 8B alignment; offs padded so sums is 16B-aligned)
    unsigned long long* binned = (unsigned long long*)d_ws;         // NBKT*BKT_CAP (8 MB)
    int*   cursor  = (int*)(binned + (size_t)NBKT * BKT_CAP);       // [NBKT]
    int*   offs    = cursor + NBKT;                                 // [N_NODES+1] pad->50004
    int*   deg     = offs + 50004;                                  // [N_NODES]
    int*   csr_src = deg + N_NODES;                                 // [N_EDGES]
    float* sums    = (float*)(csr_src + N_EDGES);                   // [N_NODES*IN_CH]

    hipMemsetAsync(cursor, 0, NBKT * sizeof(int), stream);
    bin_kernel<<<NBIN_BLOCKS, 256, 0, stream>>>(ei, cursor, binned);
    csr_build_kernel<<<NBKT, 256, 0, stream>>>(binned, cursor, offs, deg, csr_src);
    gather_sum_kernel<<<N_NODES / 16, 256, 0, stream>>>(x, csr_src, offs, sums);
    gemm_kernel<<<N_NODES / 16, 256, 0, stream>>>(sums, deg, W, out);
}